// Round 12
// baseline (124.869 us; speedup 1.0000x reference)
//
#include <hip/hip_runtime.h>
#include <math.h>

// NLM S=21, 256x256x3, reflect padding. Round 12 = R11 + strip-8 dual-offset v:
// - v-phase: waves 0-1 -> offset A, waves 2-3 -> offset B; 8-row strips
//   (7 aligned b64-mergeable hs reads + 7 fp16 slide steps per thread)
// - RSTR 54->52: 104B rows, 8B aligned (b64 merge provable), __align__(16)
// - A/B accumulator halves combined via reused Creg LDS at epilogue
// - h-phase (persistent y0, packed ff, fp16 slide chain), NG=16, direct-store,
//   unrolled finalize all as R11

#define IMG 256
#define NPIX (IMG * IMG)
#define TILE 32
#define GR 52      // window-grid dim
#define YD 72      // staged Y rows/cols
#define YSTR 78    // Yreg row stride in halves (39 dwords, odd -> full bank spread)
#define RSTR 52    // hs row stride in halves (104B rows, 8B-aligned -> b64 merge)
#define NOFF 441
#define NG 16

typedef __attribute__((ext_vector_type(4))) _Float16 half4;
typedef __attribute__((ext_vector_type(2))) _Float16 half2_t;

#if __has_builtin(__builtin_amdgcn_fdot2)
#define FDOT2(a, b, c) __builtin_amdgcn_fdot2((a), (b), (c), false)
#else
#define FDOT2(a, b, c) ((c) + (float)(a).x * (float)(b).x + (float)(a).y * (float)(b).y)
#endif

__device__ __forceinline__ int refl(int t) {
    t = t < 0 ? -t : t;             // valid for t in [-255, 510]
    return t > 255 ? 510 - t : t;
}

template <bool DIRECT>
__global__ __launch_bounds__(256, 4)
void nlm_main(const float* __restrict__ rgb, const float* __restrict__ hptr,
              float4* __restrict__ partials)
{
    __shared__ __align__(16) _Float16 Yreg[YD][YSTR];       // 11232 B
    __shared__ __align__(16) _Float16 Creg4[GR][GR][4];     // 21632 B (also epilogue scratch)
    __shared__ __align__(16) _Float16 hsAB[2][TILE][RSTR];  //  6656 B (A/B h-sums)
    __shared__ unsigned char cjTab[21][GR];                 //  1092 B
    // total 40612 B -> 4 blocks/CU

    const int tid = threadIdx.x;
    const int tj = ((int)blockIdx.x & 7) * TILE;
    const int ti = ((int)blockIdx.x >> 3) * TILE;

    const int Ybi = min(max(ti - 20, 0), IMG - YD);
    const int Ybj = min(max(tj - 20, 0), IMG - YD);
    const bool interior = (ti >= 20) && (ti + 51 <= 255) && (tj >= 20) && (tj + 51 <= 255);

    // ---- stage Y (clipped luminance, fp16) ----
    for (int idx = tid; idx < YD * YD; idx += 256) {
        int a = idx / YD, b = idx - a * YD;
        int g = (Ybi + a) * IMG + (Ybj + b);
        float r  = fminf(fmaxf(rgb[g], 0.f), 1.f);
        float gg = fminf(fmaxf(rgb[NPIX + g], 0.f), 1.f);
        float bb = fminf(fmaxf(rgb[2 * NPIX + g], 0.f), 1.f);
        Yreg[a][b] = (_Float16)(0.299f * r + 0.587f * gg + 0.114f * bb);
    }
    // ---- stage RGBX taps at window-grid coords (UNclipped rgb) ----
    for (int idx = tid; idx < GR * GR; idx += 256) {
        int t = idx / GR, b = idx - t * GR;
        int g = refl(ti - 10 + t) * IMG + refl(tj - 10 + b);
        half4 c;
        c.x = (_Float16)rgb[g];
        c.y = (_Float16)rgb[NPIX + g];
        c.z = (_Float16)rgb[2 * NPIX + g];
        c.w = (_Float16)0.f;
        *(half4*)&Creg4[t][b][0] = c;
    }
    // ---- col refl maps for all dv (edge tiles) ----
    if (!interior) {
        for (int idx = tid; idx < 21 * GR; idx += 256) {
            int d = idx / GR, c = idx - d * GR;
            cjTab[d][c] = (unsigned char)(refl(refl(tj - 10 + c) + (d - 10)) - Ybj);
        }
    }
    __syncthreads();   // staging complete

    const int lane = tid & 63;
    const int hw   = tid >> 6;               // wave id 0..3
    const bool hactive = (lane < GR) && (hw < 2);

    // ---- persistent y0 row (offset-invariant), 26 half2 regs (waves 0-1) ----
    half2_t y0h[26];
    if (hactive) {
        if (interior) {
            const half2_t* q0 = (const half2_t*)&Yreg[lane + 10][10];  // even offset
            #pragma unroll
            for (int i = 0; i < 26; ++i) y0h[i] = q0[i];
        } else {
            const _Float16* Y0row = &Yreg[refl(ti - 10 + lane) - Ybi][0];
            const unsigned char* cj0 = &cjTab[10][0];
            #pragma unroll
            for (int i = 0; i < 26; ++i) {
                half2_t v;
                v.x = Y0row[cj0[2 * i]];
                v.y = Y0row[cj0[2 * i + 1]];
                y0h[i] = v;
            }
        }
    }

    const float hv = fmaxf(hptr[0], 0.f);
    const float negI = -1.0f / (hv + 1e-8f);

    // v decomposition: half = offset stream (0=A waves 0-1, 1=B waves 2-3)
    const int vhalf = tid >> 7;
    const int vt    = tid & 127;
    const int pb    = vt & 31;               // pixel col
    const int s8    = ((vt >> 5) & 3) << 3;  // strip start row (0,8,16,24)
    float aR[8], aG[8], aB[8], aW[8];
    #pragma unroll
    for (int k = 0; k < 8; ++k) { aR[k] = 0.f; aG[k] = 0.f; aB[k] = 0.f; aW[k] = 0.f; }

    half2_t one; one.x = (_Float16)1.f; one.y = (_Float16)1.f;

    auto do_h = [&](int du, int dv, int buf) {
        const int t = lane;
        _Float16* hsb = &hsAB[buf][0][0];
        half2_t ff[26];                       // packed f-row: 13 VGPRs
        if (interior) {
            if ((dv & 1) == 0) {
                const half2_t* q1 = (const half2_t*)&Yreg[t + 10 + du][10 + dv];
                #pragma unroll
                for (int i = 0; i < 26; ++i) {
                    half2_t d2 = y0h[i] - q1[i];
                    ff[i] = d2 * d2;
                }
            } else {
                const half2_t* q1 = (const half2_t*)&Yreg[t + 10 + du][10 + dv - 1];
                half2_t prev = q1[0];
                #pragma unroll
                for (int i = 0; i < 26; ++i) {
                    half2_t cur = q1[i + 1];
                    half2_t b; b.x = prev.y; b.y = cur.x;
                    half2_t d2 = y0h[i] - b;
                    ff[i] = d2 * d2;
                    prev = cur;
                }
            }
        } else {
            const unsigned int* cw = (const unsigned int*)&cjTab[dv + 10][0];  // wave-uniform
            const _Float16* Y1row = &Yreg[refl(refl(ti - 10 + t) + du) - Ybi][0];
            #pragma unroll
            for (int i = 0; i < 26; ++i) {
                unsigned int w0 = cw[i >> 1];
                int sh = (i & 1) * 16;
                _Float16 a0 = Y1row[(w0 >> sh) & 0xffu];
                _Float16 a1 = Y1row[(w0 >> (sh + 8)) & 0xffu];
                half2_t yv; yv.x = a0; yv.y = a1;
                half2_t d2 = y0h[i] - yv;
                ff[i] = d2 * d2;
            }
        }
        // initial sum f[0..20] exact in f32
        float s0f = 0.f;
        #pragma unroll
        for (int i = 0; i < 10; ++i) s0f = FDOT2(ff[i], one, s0f);
        s0f += (float)ff[10].x;
        _Float16 s = (_Float16)s0f;
        hsb[t] = s;                           // c = 0
        #pragma unroll
        for (int k = 1; k < 32; ++k) {
            int ja = 20 + k, jb = k - 1;
            _Float16 fa = (ja & 1) ? ff[ja >> 1].y : ff[ja >> 1].x;
            _Float16 fb = (jb & 1) ? ff[jb >> 1].y : ff[jb >> 1].x;
            s += (_Float16)(fa - fb);
            hsb[k * RSTR + t] = s;
        }
    };

    auto do_v = [&](int du, int dv, int buf) {
        const half2_t* col2 = (const half2_t*)&hsAB[buf][pb][s8];  // 8B-aligned base
        half2_t w2[14];                       // 28 halves: rows s8..s8+27
        #pragma unroll
        for (int i = 0; i < 14; ++i) w2[i] = col2[i];

        float vs = 0.f;
        #pragma unroll
        for (int i = 0; i < 10; ++i) vs = FDOT2(w2[i], one, vs);
        vs += (float)w2[10].x;

        float vss[8];
        vss[0] = vs;
        #pragma unroll
        for (int k = 0; k < 7; ++k) {
            int ja = 21 + k, jb = k;
            _Float16 fa = (ja & 1) ? w2[ja >> 1].y : w2[ja >> 1].x;
            _Float16 fb = (jb & 1) ? w2[jb >> 1].y : w2[jb >> 1].x;
            vss[k + 1] = vss[k] + (float)(_Float16)(fa - fb);
        }

        const int cr = s8 + 10 + du;
        const int cc = pb + 10 + dv;
        #pragma unroll
        for (int k = 0; k < 8; ++k) {
            float dist = sqrtf(fmaxf(vss[k], 0.f));
            float w = __expf(dist * negI);
            half4 c = *(const half4*)&Creg4[cr + k][cc][0];
            aW[k] += w;
            aR[k] += w * (float)c.x;
            aG[k] += w * (float)c.y;
            aB[k] += w * (float)c.z;
        }
    };

    int duA = -10, dvA = (int)blockIdx.y - 10;

    for (int oA = (int)blockIdx.y; oA < NOFF; oA += 2 * NG) {
        int duB = duA, dvB = dvA + NG;
        if (dvB > 10) { dvB -= 21; duB += 1; }
        const bool hasB = (oA + NG) < NOFF;

        __syncthreads();   // hs buffers free (prev round's v done)

        if (hactive && (hasB || hw == 0))
            do_h(hw ? duB : duA, hw ? dvB : dvA, hw);

        __syncthreads();   // hs visible

        if (vhalf == 0)      do_v(duA, dvA, 0);
        else if (hasB)       do_v(duB, dvB, 1);

        // advance A by 32 offsets
        duA += 1; dvA += 11;
        if (dvA > 10) { dvA -= 21; duA += 1; }
    }

    // ---- epilogue: combine A/B halves via reused Creg LDS, waves 2-3 store ----
    __syncthreads();                          // all taps read; Creg4 reusable
    float4* ered = (float4*)&Creg4[0][0][0];  // 1024 x float4 = 16384 B
    if (vhalf == 0) {
        #pragma unroll
        for (int k = 0; k < 8; ++k)
            ered[vt * 8 + k] = make_float4(aR[k], aG[k], aB[k], aW[k]);
    }
    __syncthreads();
    if (vhalf == 1) {
        #pragma unroll
        for (int k = 0; k < 8; ++k) {
            float4 a = ered[vt * 8 + k];
            float4 st = make_float4(a.x + aR[k], a.y + aG[k], a.z + aB[k], a.w + aW[k]);
            int gpix = (ti + s8 + k) * IMG + (tj + pb);
            if (DIRECT) {
                partials[(size_t)blockIdx.y * NPIX + gpix] = st;
            } else {
                float* p = (float*)&partials[gpix];
                atomicAdd(p + 0, st.x);
                atomicAdd(p + 1, st.y);
                atomicAdd(p + 2, st.z);
                atomicAdd(p + 3, st.w);
            }
        }
    }
}

template <int NGT>
__global__ __launch_bounds__(256)
void nlm_finalize(const float4* __restrict__ partials, float* __restrict__ out)
{
    int idx = blockIdx.x * blockDim.x + threadIdx.x;
    float r = 0.f, g = 0.f, b = 0.f, w = 0.f;
    #pragma unroll
    for (int gg = 0; gg < NGT; ++gg) {
        float4 p = partials[(size_t)gg * NPIX + idx];
        r += p.x; g += p.y; b += p.z; w += p.w;
    }
    float inv = 1.0f / w;   // sum(w) >= 1 (self offset contributes exp(0))
    out[idx]            = fminf(fmaxf(r * inv, 0.f), 1.f);
    out[NPIX + idx]     = fminf(fmaxf(g * inv, 0.f), 1.f);
    out[2 * NPIX + idx] = fminf(fmaxf(b * inv, 0.f), 1.f);
}

extern "C" void kernel_launch(void* const* d_in, const int* in_sizes, int n_in,
                              void* d_out, int out_size, void* d_ws, size_t ws_size,
                              hipStream_t stream) {
    (void)in_sizes; (void)n_in; (void)out_size;
    const float* rgb  = (const float*)d_in[0];
    const float* hptr = (const float*)d_in[1];
    float* out = (float*)d_out;
    float4* partials = (float4*)d_ws;

    const bool direct = ws_size >= (size_t)NG * NPIX * sizeof(float4);  // 16.8 MB
    dim3 grid(64, NG);
    if (direct) {
        nlm_main<true><<<grid, 256, 0, stream>>>(rgb, hptr, partials);
        nlm_finalize<NG><<<NPIX / 256, 256, 0, stream>>>(partials, out);
    } else {
        (void)hipMemsetAsync(partials, 0, (size_t)NPIX * sizeof(float4), stream);
        nlm_main<false><<<grid, 256, 0, stream>>>(rgb, hptr, partials);
        nlm_finalize<1><<<NPIX / 256, 256, 0, stream>>>(partials, out);
    }
}

// Round 13
// 114.178 us; speedup vs baseline: 1.0936x; 1.0936x over previous
//
#include <hip/hip_runtime.h>
#include <math.h>

// NLM S=21, 256x256x3, reflect padding. Round 13: BARRIER-FREE hot loop.
// One wave owns one tile-offset end-to-end: h (row-lanes) -> private LDS strip
// -> v (col-lanes, 16 px/lane) in the same wave; within-wave DS is in-order,
// so no __syncthreads in the loop. 4 offset streams per block (one per wave),
// 48 streams total (grid.y=12). Block-level wave merge at epilogue only.

#define IMG 256
#define NPIX (IMG * IMG)
#define TILE 32
#define GR 52      // window-grid dim
#define YD 72      // staged Y rows/cols
#define YSTR 78    // Yreg row stride in halves (39 dwords, odd -> full bank spread)
#define HST 54     // hsT t-stride in halves (27 dwords, odd -> full bank spread)
#define NOFF 441
#define NGB 12     // offset groups (grid.y); 4 wave-streams each -> 48 streams

typedef __attribute__((ext_vector_type(4))) _Float16 half4;
typedef __attribute__((ext_vector_type(2))) _Float16 half2_t;

#if __has_builtin(__builtin_amdgcn_fdot2)
#define FDOT2(a, b, c) __builtin_amdgcn_fdot2((a), (b), (c), false)
#else
#define FDOT2(a, b, c) ((c) + (float)(a).x * (float)(b).x + (float)(a).y * (float)(b).y)
#endif

__device__ __forceinline__ int refl(int t) {
    t = t < 0 ? -t : t;             // valid for t in [-255, 510]
    return t > 255 ? 510 - t : t;
}

template <bool DIRECT>
__global__ __launch_bounds__(256, 3)
void nlm_main(const float* __restrict__ rgb, const float* __restrict__ hptr,
              float4* __restrict__ partials)
{
    __shared__ __align__(16) _Float16 Yreg[YD][YSTR];      // 11232 B
    __shared__ __align__(16) _Float16 Creg4[GR][GR][4];    // 21632 B (epilogue scratch too)
    __shared__ __align__(16) _Float16 hsT[4][TILE][HST];   // 13824 B (private per wave)
    __shared__ unsigned char cjTab[21][GR];                //  1092 B
    // total 47780 B -> 3 blocks/CU

    const int tid = threadIdx.x;
    const int tj = ((int)blockIdx.x & 7) * TILE;
    const int ti = ((int)blockIdx.x >> 3) * TILE;

    const int Ybi = min(max(ti - 20, 0), IMG - YD);
    const int Ybj = min(max(tj - 20, 0), IMG - YD);
    const bool interior = (ti >= 20) && (ti + 51 <= 255) && (tj >= 20) && (tj + 51 <= 255);

    // ---- stage Y (clipped luminance, fp16) ----
    for (int idx = tid; idx < YD * YD; idx += 256) {
        int a = idx / YD, b = idx - a * YD;
        int g = (Ybi + a) * IMG + (Ybj + b);
        float r  = fminf(fmaxf(rgb[g], 0.f), 1.f);
        float gg = fminf(fmaxf(rgb[NPIX + g], 0.f), 1.f);
        float bb = fminf(fmaxf(rgb[2 * NPIX + g], 0.f), 1.f);
        Yreg[a][b] = (_Float16)(0.299f * r + 0.587f * gg + 0.114f * bb);
    }
    // ---- stage RGBX taps at window-grid coords (UNclipped rgb) ----
    for (int idx = tid; idx < GR * GR; idx += 256) {
        int t = idx / GR, b = idx - t * GR;
        int g = refl(ti - 10 + t) * IMG + refl(tj - 10 + b);
        half4 c;
        c.x = (_Float16)rgb[g];
        c.y = (_Float16)rgb[NPIX + g];
        c.z = (_Float16)rgb[2 * NPIX + g];
        c.w = (_Float16)0.f;
        *(half4*)&Creg4[t][b][0] = c;
    }
    // ---- col refl maps for all dv (edge tiles) ----
    if (!interior) {
        for (int idx = tid; idx < 21 * GR; idx += 256) {
            int d = idx / GR, c = idx - d * GR;
            cjTab[d][c] = (unsigned char)(refl(refl(tj - 10 + c) + (d - 10)) - Ybj);
        }
    }
    __syncthreads();   // staging complete — last barrier before epilogue

    const int lane = tid & 63;
    const int wv   = tid >> 6;               // wave id 0..3
    const bool hact = lane < GR;

    // ---- persistent y0 row (offset-invariant), 13 VGPRs ----
    half2_t y0h[26];
    if (hact) {
        if (interior) {
            const half2_t* q0 = (const half2_t*)&Yreg[lane + 10][10];
            #pragma unroll
            for (int i = 0; i < 26; ++i) y0h[i] = q0[i];
        } else {
            const _Float16* Y0row = &Yreg[refl(ti - 10 + lane) - Ybi][0];
            const unsigned char* cj0 = &cjTab[10][0];
            #pragma unroll
            for (int i = 0; i < 26; ++i) {
                half2_t v;
                v.x = Y0row[cj0[2 * i]];
                v.y = Y0row[cj0[2 * i + 1]];
                y0h[i] = v;
            }
        }
    }

    const float hv = fmaxf(hptr[0], 0.f);
    const float negI = -1.0f / (hv + 1e-8f);

    // v decomposition: lane -> (col pb, 16-row strip)
    const int pb  = lane & 31;
    const int s16 = (lane >> 5) << 4;        // 0 or 16

    float aR[16], aG[16], aB[16], aW[16];
    #pragma unroll
    for (int k = 0; k < 16; ++k) { aR[k]=0.f; aG[k]=0.f; aB[k]=0.f; aW[k]=0.f; }

    half2_t one; one.x = (_Float16)1.f; one.y = (_Float16)1.f;

    // ---- barrier-free offset loop: this wave owns offsets o = base + 48k ----
    for (int o = (int)blockIdx.y * 4 + wv; o < NOFF; o += 48) {
        const int oq = o / 21;
        const int du = oq - 10;
        const int dv = o - oq * 21 - 10;

        // ===== h-phase: lane = window row t, writes 32 col-sums to own strip =====
        if (hact) {
            const int t = lane;
            half2_t ff[26];
            if (interior) {
                if ((dv & 1) == 0) {
                    const half2_t* q1 = (const half2_t*)&Yreg[t + 10 + du][10 + dv];
                    #pragma unroll
                    for (int i = 0; i < 26; ++i) {
                        half2_t d2 = y0h[i] - q1[i];
                        ff[i] = d2 * d2;
                    }
                } else {
                    const half2_t* q1 = (const half2_t*)&Yreg[t + 10 + du][10 + dv - 1];
                    half2_t prev = q1[0];
                    #pragma unroll
                    for (int i = 0; i < 26; ++i) {
                        half2_t cur = q1[i + 1];
                        half2_t b; b.x = prev.y; b.y = cur.x;
                        half2_t d2 = y0h[i] - b;
                        ff[i] = d2 * d2;
                        prev = cur;
                    }
                }
            } else {
                const unsigned int* cw = (const unsigned int*)&cjTab[dv + 10][0];
                const _Float16* Y1row = &Yreg[refl(refl(ti - 10 + t) + du) - Ybi][0];
                #pragma unroll
                for (int i = 0; i < 26; ++i) {
                    unsigned int w0 = cw[i >> 1];
                    int sh = (i & 1) * 16;
                    _Float16 a0 = Y1row[(w0 >> sh) & 0xffu];
                    _Float16 a1 = Y1row[(w0 >> (sh + 8)) & 0xffu];
                    half2_t yv; yv.x = a0; yv.y = a1;
                    half2_t d2 = y0h[i] - yv;
                    ff[i] = d2 * d2;
                }
            }
            float s0f = 0.f;
            #pragma unroll
            for (int i = 0; i < 10; ++i) s0f = FDOT2(ff[i], one, s0f);
            s0f += (float)ff[10].x;
            _Float16 s = (_Float16)s0f;
            hsT[wv][0][t] = s;
            #pragma unroll
            for (int k = 1; k < 32; ++k) {
                int ja = 20 + k, jb = k - 1;
                _Float16 fa = (ja & 1) ? ff[ja >> 1].y : ff[ja >> 1].x;
                _Float16 fb = (jb & 1) ? ff[jb >> 1].y : ff[jb >> 1].x;
                s += (_Float16)(fa - fb);
                hsT[wv][k][t] = s;
            }
        }

        // ===== v-phase: same wave, in-order DS -> no barrier needed =====
        {
            const half2_t* col2 = (const half2_t*)&hsT[wv][pb][s16];
            half2_t w2[18];                  // rows s16 .. s16+35
            #pragma unroll
            for (int i = 0; i < 18; ++i) w2[i] = col2[i];

            float vs = 0.f;
            #pragma unroll
            for (int i = 0; i < 10; ++i) vs = FDOT2(w2[i], one, vs);
            vs += (float)w2[10].x;

            float vss[16];
            vss[0] = vs;
            #pragma unroll
            for (int k = 0; k < 15; ++k) {
                int ja = 21 + k, jb = k;
                _Float16 fa = (ja & 1) ? w2[ja >> 1].y : w2[ja >> 1].x;
                _Float16 fb = (jb & 1) ? w2[jb >> 1].y : w2[jb >> 1].x;
                vss[k + 1] = vss[k] + (float)(_Float16)(fa - fb);
            }

            const int cr = s16 + 10 + du;
            const int cc = pb + 10 + dv;
            #pragma unroll
            for (int k = 0; k < 16; ++k) {
                float dist = sqrtf(fmaxf(vss[k], 0.f));
                float w = __expf(dist * negI);
                half4 c = *(const half4*)&Creg4[cr + k][cc][0];
                aW[k] += w;
                aR[k] += w * (float)c.x;
                aG[k] += w * (float)c.y;
                aB[k] += w * (float)c.z;
            }
        }
    }

    // ---- epilogue: merge 4 wave-streams via reused Creg LDS ----
    __syncthreads();                          // all taps consumed; Creg4 reusable
    float4* scratch = (float4*)&Creg4[0][0][0];   // 1024 x float4 = 16384 B
    #pragma unroll
    for (int w = 0; w < 4; ++w) {
        if (wv == w) {
            #pragma unroll
            for (int k = 0; k < 16; ++k) {
                int px = (s16 + k) * 32 + pb;
                float4 v = make_float4(aR[k], aG[k], aB[k], aW[k]);
                if (w == 0) scratch[px] = v;
                else {
                    float4 a = scratch[px];
                    scratch[px] = make_float4(a.x + v.x, a.y + v.y, a.z + v.z, a.w + v.w);
                }
            }
        }
        __syncthreads();
    }
    // ---- store: one float4 per pixel, coalesced ----
    for (int i = tid; i < TILE * TILE; i += 256) {
        float4 v = scratch[i];
        int gpix = (ti + (i >> 5)) * IMG + (tj + (i & 31));
        if (DIRECT) {
            partials[(size_t)blockIdx.y * NPIX + gpix] = v;
        } else {
            float* p = (float*)&partials[gpix];
            atomicAdd(p + 0, v.x);
            atomicAdd(p + 1, v.y);
            atomicAdd(p + 2, v.z);
            atomicAdd(p + 3, v.w);
        }
    }
}

template <int NGT>
__global__ __launch_bounds__(256)
void nlm_finalize(const float4* __restrict__ partials, float* __restrict__ out)
{
    int idx = blockIdx.x * blockDim.x + threadIdx.x;
    float r = 0.f, g = 0.f, b = 0.f, w = 0.f;
    #pragma unroll
    for (int gg = 0; gg < NGT; ++gg) {
        float4 p = partials[(size_t)gg * NPIX + idx];
        r += p.x; g += p.y; b += p.z; w += p.w;
    }
    float inv = 1.0f / w;   // sum(w) >= 1 (self offset contributes exp(0))
    out[idx]            = fminf(fmaxf(r * inv, 0.f), 1.f);
    out[NPIX + idx]     = fminf(fmaxf(g * inv, 0.f), 1.f);
    out[2 * NPIX + idx] = fminf(fmaxf(b * inv, 0.f), 1.f);
}

extern "C" void kernel_launch(void* const* d_in, const int* in_sizes, int n_in,
                              void* d_out, int out_size, void* d_ws, size_t ws_size,
                              hipStream_t stream) {
    (void)in_sizes; (void)n_in; (void)out_size;
    const float* rgb  = (const float*)d_in[0];
    const float* hptr = (const float*)d_in[1];
    float* out = (float*)d_out;
    float4* partials = (float4*)d_ws;

    const bool direct = ws_size >= (size_t)NGB * NPIX * sizeof(float4);  // 12.6 MB
    dim3 grid(64, NGB);   // 768 blocks = exactly 3 blocks/CU
    if (direct) {
        nlm_main<true><<<grid, 256, 0, stream>>>(rgb, hptr, partials);
        nlm_finalize<NGB><<<NPIX / 256, 256, 0, stream>>>(partials, out);
    } else {
        (void)hipMemsetAsync(partials, 0, (size_t)NPIX * sizeof(float4), stream);
        nlm_main<false><<<grid, 256, 0, stream>>>(rgb, hptr, partials);
        nlm_finalize<1><<<NPIX / 256, 256, 0, stream>>>(partials, out);
    }
}

// Round 14
// 112.152 us; speedup vs baseline: 1.1134x; 1.0181x over previous
//
#include <hip/hip_runtime.h>
#include <math.h>

// NLM S=21, 256x256x3, reflect padding. Round 14 = R13 barrier-free + ILP:
// - h slide chain split in two (seeds k=0, k=16) -> 2 independent 15-step chains
// - v slide chain split in two (seeds k=0, k=8)  -> 2 independent 7-step chains
// - packed fp16 tap accumulation: taps staged (R,G,B,1); acc via v_pk_fma_f16
//   (accRG, accBW), converted to f32 only at the epilogue merge
// - one wave owns one tile-offset end-to-end; no __syncthreads in hot loop

#define IMG 256
#define NPIX (IMG * IMG)
#define TILE 32
#define GR 52      // window-grid dim
#define YD 72      // staged Y rows/cols
#define YSTR 78    // Yreg row stride in halves (39 dwords, odd -> full bank spread)
#define HST 54     // hsT t-stride in halves (27 dwords, odd -> full bank spread)
#define NOFF 441
#define NGB 12     // offset groups (grid.y); 4 wave-streams each -> 48 streams

typedef __attribute__((ext_vector_type(4))) _Float16 half4;
typedef __attribute__((ext_vector_type(2))) _Float16 half2_t;

#if __has_builtin(__builtin_amdgcn_fdot2)
#define FDOT2(a, b, c) __builtin_amdgcn_fdot2((a), (b), (c), false)
#else
#define FDOT2(a, b, c) ((c) + (float)(a).x * (float)(b).x + (float)(a).y * (float)(b).y)
#endif

__device__ __forceinline__ int refl(int t) {
    t = t < 0 ? -t : t;             // valid for t in [-255, 510]
    return t > 255 ? 510 - t : t;
}

template <bool DIRECT>
__global__ __launch_bounds__(256, 3)
void nlm_main(const float* __restrict__ rgb, const float* __restrict__ hptr,
              float4* __restrict__ partials)
{
    __shared__ __align__(16) _Float16 Yreg[YD][YSTR];      // 11232 B
    __shared__ __align__(16) _Float16 Creg4[GR][GR][4];    // 21632 B (epilogue scratch too)
    __shared__ __align__(16) _Float16 hsT[4][TILE][HST];   // 13824 B (private per wave)
    __shared__ unsigned char cjTab[21][GR];                //  1092 B
    // total 47780 B -> 3 blocks/CU

    const int tid = threadIdx.x;
    const int tj = ((int)blockIdx.x & 7) * TILE;
    const int ti = ((int)blockIdx.x >> 3) * TILE;

    const int Ybi = min(max(ti - 20, 0), IMG - YD);
    const int Ybj = min(max(tj - 20, 0), IMG - YD);
    const bool interior = (ti >= 20) && (ti + 51 <= 255) && (tj >= 20) && (tj + 51 <= 255);

    // ---- stage Y (clipped luminance, fp16) ----
    for (int idx = tid; idx < YD * YD; idx += 256) {
        int a = idx / YD, b = idx - a * YD;
        int g = (Ybi + a) * IMG + (Ybj + b);
        float r  = fminf(fmaxf(rgb[g], 0.f), 1.f);
        float gg = fminf(fmaxf(rgb[NPIX + g], 0.f), 1.f);
        float bb = fminf(fmaxf(rgb[2 * NPIX + g], 0.f), 1.f);
        Yreg[a][b] = (_Float16)(0.299f * r + 0.587f * gg + 0.114f * bb);
    }
    // ---- stage RGB1 taps at window-grid coords (UNclipped rgb; w-slot = 1) ----
    for (int idx = tid; idx < GR * GR; idx += 256) {
        int t = idx / GR, b = idx - t * GR;
        int g = refl(ti - 10 + t) * IMG + refl(tj - 10 + b);
        half4 c;
        c.x = (_Float16)rgb[g];
        c.y = (_Float16)rgb[NPIX + g];
        c.z = (_Float16)rgb[2 * NPIX + g];
        c.w = (_Float16)1.f;                   // weight accumulator partner
        *(half4*)&Creg4[t][b][0] = c;
    }
    // ---- col refl maps for all dv (edge tiles) ----
    if (!interior) {
        for (int idx = tid; idx < 21 * GR; idx += 256) {
            int d = idx / GR, c = idx - d * GR;
            cjTab[d][c] = (unsigned char)(refl(refl(tj - 10 + c) + (d - 10)) - Ybj);
        }
    }
    __syncthreads();   // staging complete — last barrier before epilogue

    const int lane = tid & 63;
    const int wv   = tid >> 6;               // wave id 0..3
    const bool hact = lane < GR;

    // ---- persistent y0 row (offset-invariant), 13 VGPRs ----
    half2_t y0h[26];
    if (hact) {
        if (interior) {
            const half2_t* q0 = (const half2_t*)&Yreg[lane + 10][10];
            #pragma unroll
            for (int i = 0; i < 26; ++i) y0h[i] = q0[i];
        } else {
            const _Float16* Y0row = &Yreg[refl(ti - 10 + lane) - Ybi][0];
            const unsigned char* cj0 = &cjTab[10][0];
            #pragma unroll
            for (int i = 0; i < 26; ++i) {
                half2_t v;
                v.x = Y0row[cj0[2 * i]];
                v.y = Y0row[cj0[2 * i + 1]];
                y0h[i] = v;
            }
        }
    }

    const float hv = fmaxf(hptr[0], 0.f);
    const float negI = -1.0f / (hv + 1e-8f);

    // v decomposition: lane -> (col pb, 16-row strip)
    const int pb  = lane & 31;
    const int s16 = (lane >> 5) << 4;        // 0 or 16

    half2_t accRG[16], accBW[16];            // packed fp16 accumulators (32 VGPRs)
    #pragma unroll
    for (int k = 0; k < 16; ++k) {
        accRG[k].x = (_Float16)0.f; accRG[k].y = (_Float16)0.f;
        accBW[k].x = (_Float16)0.f; accBW[k].y = (_Float16)0.f;
    }

    half2_t one; one.x = (_Float16)1.f; one.y = (_Float16)1.f;

    // ---- barrier-free offset loop: this wave owns offsets o = base + 48k ----
    for (int o = (int)blockIdx.y * 4 + wv; o < NOFF; o += 48) {
        const int oq = o / 21;
        const int du = oq - 10;
        const int dv = o - oq * 21 - 10;

        // ===== h-phase: lane = window row t, writes 32 col-sums to own strip =====
        if (hact) {
            const int t = lane;
            half2_t ff[26];
            if (interior) {
                if ((dv & 1) == 0) {
                    const half2_t* q1 = (const half2_t*)&Yreg[t + 10 + du][10 + dv];
                    #pragma unroll
                    for (int i = 0; i < 26; ++i) {
                        half2_t d2 = y0h[i] - q1[i];
                        ff[i] = d2 * d2;
                    }
                } else {
                    const half2_t* q1 = (const half2_t*)&Yreg[t + 10 + du][10 + dv - 1];
                    half2_t prev = q1[0];
                    #pragma unroll
                    for (int i = 0; i < 26; ++i) {
                        half2_t cur = q1[i + 1];
                        half2_t b; b.x = prev.y; b.y = cur.x;
                        half2_t d2 = y0h[i] - b;
                        ff[i] = d2 * d2;
                        prev = cur;
                    }
                }
            } else {
                const unsigned int* cw = (const unsigned int*)&cjTab[dv + 10][0];
                const _Float16* Y1row = &Yreg[refl(refl(ti - 10 + t) + du) - Ybi][0];
                #pragma unroll
                for (int i = 0; i < 26; ++i) {
                    unsigned int w0 = cw[i >> 1];
                    int sh = (i & 1) * 16;
                    _Float16 a0 = Y1row[(w0 >> sh) & 0xffu];
                    _Float16 a1 = Y1row[(w0 >> (sh + 8)) & 0xffu];
                    half2_t yv; yv.x = a0; yv.y = a1;
                    half2_t d2 = y0h[i] - yv;
                    ff[i] = d2 * d2;
                }
            }
            // two independent seeds: k=0 (f0..f20), k=16 (f16..f36)
            float s0f = 0.f, s1f = 0.f;
            #pragma unroll
            for (int i = 0; i < 10; ++i) s0f = FDOT2(ff[i], one, s0f);
            s0f += (float)ff[10].x;
            #pragma unroll
            for (int i = 8; i < 18; ++i) s1f = FDOT2(ff[i], one, s1f);
            s1f += (float)ff[18].x;
            _Float16 sA = (_Float16)s0f;
            _Float16 sB = (_Float16)s1f;
            hsT[wv][0][t]  = sA;
            hsT[wv][16][t] = sB;
            // two independent 15-step fp16 chains
            #pragma unroll
            for (int k = 1; k < 16; ++k) {
                {
                    int ja = 20 + k, jb = k - 1;
                    _Float16 fa = (ja & 1) ? ff[ja >> 1].y : ff[ja >> 1].x;
                    _Float16 fb = (jb & 1) ? ff[jb >> 1].y : ff[jb >> 1].x;
                    sA += (_Float16)(fa - fb);
                    hsT[wv][k][t] = sA;
                }
                {
                    int ja = 36 + k, jb = 15 + k;
                    _Float16 fa = (ja & 1) ? ff[ja >> 1].y : ff[ja >> 1].x;
                    _Float16 fb = (jb & 1) ? ff[jb >> 1].y : ff[jb >> 1].x;
                    sB += (_Float16)(fa - fb);
                    hsT[wv][16 + k][t] = sB;
                }
            }
        }

        // ===== v-phase: same wave, in-order DS -> no barrier needed =====
        {
            const half2_t* col2 = (const half2_t*)&hsT[wv][pb][s16];
            half2_t w2[18];                  // rows s16 .. s16+35
            #pragma unroll
            for (int i = 0; i < 18; ++i) w2[i] = col2[i];

            // two independent seeds: rows 0..20 and rows 8..28 (relative)
            float vs0 = 0.f, vs1 = 0.f;
            #pragma unroll
            for (int i = 0; i < 10; ++i) vs0 = FDOT2(w2[i], one, vs0);
            vs0 += (float)w2[10].x;
            #pragma unroll
            for (int i = 4; i < 14; ++i) vs1 = FDOT2(w2[i], one, vs1);
            vs1 += (float)w2[14].x;

            float vss[16];
            vss[0] = vs0;
            vss[8] = vs1;
            #pragma unroll
            for (int k = 0; k < 7; ++k) {
                {   // chain A: vss[1..7]
                    int ja = 21 + k, jb = k;
                    _Float16 fa = (ja & 1) ? w2[ja >> 1].y : w2[ja >> 1].x;
                    _Float16 fb = (jb & 1) ? w2[jb >> 1].y : w2[jb >> 1].x;
                    vss[k + 1] = vss[k] + (float)(_Float16)(fa - fb);
                }
                {   // chain B: vss[9..15]
                    int ja = 29 + k, jb = 8 + k;
                    _Float16 fa = (ja & 1) ? w2[ja >> 1].y : w2[ja >> 1].x;
                    _Float16 fb = (jb & 1) ? w2[jb >> 1].y : w2[jb >> 1].x;
                    vss[k + 9] = vss[k + 8] + (float)(_Float16)(fa - fb);
                }
            }

            const int cr = s16 + 10 + du;
            const int cc = pb + 10 + dv;
            #pragma unroll
            for (int k = 0; k < 16; ++k) {
                float dist = sqrtf(fmaxf(vss[k], 0.f));
                float w = __expf(dist * negI);
                _Float16 wh = (_Float16)w;
                half2_t w2v; w2v.x = wh; w2v.y = wh;
                const half2_t* cp = (const half2_t*)&Creg4[cr + k][cc][0];
                half2_t cRG = cp[0];         // (R, G)
                half2_t cBW = cp[1];         // (B, 1)
                accRG[k] = w2v * cRG + accRG[k];   // v_pk_fma_f16
                accBW[k] = w2v * cBW + accBW[k];
            }
        }
    }

    // ---- epilogue: merge 4 wave-streams via reused Creg LDS ----
    __syncthreads();                          // all taps consumed; Creg4 reusable
    float4* scratch = (float4*)&Creg4[0][0][0];   // 1024 x float4 = 16384 B
    #pragma unroll
    for (int w = 0; w < 4; ++w) {
        if (wv == w) {
            #pragma unroll
            for (int k = 0; k < 16; ++k) {
                int px = (s16 + k) * 32 + pb;
                float4 v = make_float4((float)accRG[k].x, (float)accRG[k].y,
                                       (float)accBW[k].x, (float)accBW[k].y);
                if (w == 0) scratch[px] = v;
                else {
                    float4 a = scratch[px];
                    scratch[px] = make_float4(a.x + v.x, a.y + v.y, a.z + v.z, a.w + v.w);
                }
            }
        }
        __syncthreads();
    }
    // ---- store: one float4 per pixel, coalesced ----
    for (int i = tid; i < TILE * TILE; i += 256) {
        float4 v = scratch[i];
        int gpix = (ti + (i >> 5)) * IMG + (tj + (i & 31));
        if (DIRECT) {
            partials[(size_t)blockIdx.y * NPIX + gpix] = v;
        } else {
            float* p = (float*)&partials[gpix];
            atomicAdd(p + 0, v.x);
            atomicAdd(p + 1, v.y);
            atomicAdd(p + 2, v.z);
            atomicAdd(p + 3, v.w);
        }
    }
}

template <int NGT>
__global__ __launch_bounds__(256)
void nlm_finalize(const float4* __restrict__ partials, float* __restrict__ out)
{
    int idx = blockIdx.x * blockDim.x + threadIdx.x;
    float r = 0.f, g = 0.f, b = 0.f, w = 0.f;
    #pragma unroll
    for (int gg = 0; gg < NGT; ++gg) {
        float4 p = partials[(size_t)gg * NPIX + idx];
        r += p.x; g += p.y; b += p.z; w += p.w;
    }
    float inv = 1.0f / w;   // sum(w) >= 1 (self offset contributes exp(0))
    out[idx]            = fminf(fmaxf(r * inv, 0.f), 1.f);
    out[NPIX + idx]     = fminf(fmaxf(g * inv, 0.f), 1.f);
    out[2 * NPIX + idx] = fminf(fmaxf(b * inv, 0.f), 1.f);
}

extern "C" void kernel_launch(void* const* d_in, const int* in_sizes, int n_in,
                              void* d_out, int out_size, void* d_ws, size_t ws_size,
                              hipStream_t stream) {
    (void)in_sizes; (void)n_in; (void)out_size;
    const float* rgb  = (const float*)d_in[0];
    const float* hptr = (const float*)d_in[1];
    float* out = (float*)d_out;
    float4* partials = (float4*)d_ws;

    const bool direct = ws_size >= (size_t)NGB * NPIX * sizeof(float4);  // 12.6 MB
    dim3 grid(64, NGB);   // 768 blocks = exactly 3 blocks/CU
    if (direct) {
        nlm_main<true><<<grid, 256, 0, stream>>>(rgb, hptr, partials);
        nlm_finalize<NGB><<<NPIX / 256, 256, 0, stream>>>(partials, out);
    } else {
        (void)hipMemsetAsync(partials, 0, (size_t)NPIX * sizeof(float4), stream);
        nlm_main<false><<<grid, 256, 0, stream>>>(rgb, hptr, partials);
        nlm_finalize<1><<<NPIX / 256, 256, 0, stream>>>(partials, out);
    }
}

// Round 15
// 108.995 us; speedup vs baseline: 1.1456x; 1.0290x over previous
//
#include <hip/hip_runtime.h>
#include <math.h>

// NLM S=21, 256x256x3, reflect padding. Round 15 = R14 hot loop repackaged:
// 512-thread blocks, 8 wave-streams per tile, 2 blocks/CU -> 16 waves/CU
// (was 12). Yreg/Creg/cjTab staged once per tile for 8 streams. Barrier-free
// hot loop verbatim from R14 (split slide chains, packed fp16 tap accum).

#define IMG 256
#define NPIX (IMG * IMG)
#define TILE 32
#define GR 52      // window-grid dim
#define YD 72      // staged Y rows/cols
#define YSTR 78    // Yreg row stride in halves (39 dwords, odd -> full bank spread)
#define HST 54     // hsT t-stride in halves (27 dwords, odd -> full bank spread)
#define NOFF 441
#define NGB 8      // offset groups (grid.y); 8 wave-streams each -> 64 streams
#define NTHR 512

typedef __attribute__((ext_vector_type(4))) _Float16 half4;
typedef __attribute__((ext_vector_type(2))) _Float16 half2_t;

#if __has_builtin(__builtin_amdgcn_fdot2)
#define FDOT2(a, b, c) __builtin_amdgcn_fdot2((a), (b), (c), false)
#else
#define FDOT2(a, b, c) ((c) + (float)(a).x * (float)(b).x + (float)(a).y * (float)(b).y)
#endif

__device__ __forceinline__ int refl(int t) {
    t = t < 0 ? -t : t;             // valid for t in [-255, 510]
    return t > 255 ? 510 - t : t;
}

template <bool DIRECT>
__global__ __launch_bounds__(NTHR, 4)
void nlm_main(const float* __restrict__ rgb, const float* __restrict__ hptr,
              float4* __restrict__ partials)
{
    __shared__ __align__(16) _Float16 Yreg[YD][YSTR];      // 11232 B
    __shared__ __align__(16) _Float16 Creg4[GR][GR][4];    // 21632 B (epilogue scratch too)
    __shared__ __align__(16) _Float16 hsT[8][TILE][HST];   // 27648 B (private per wave)
    __shared__ unsigned char cjTab[21][GR];                //  1092 B
    // total 61604 B -> 2 blocks/CU (16 waves/CU)

    const int tid = threadIdx.x;
    const int tj = ((int)blockIdx.x & 7) * TILE;
    const int ti = ((int)blockIdx.x >> 3) * TILE;

    const int Ybi = min(max(ti - 20, 0), IMG - YD);
    const int Ybj = min(max(tj - 20, 0), IMG - YD);
    const bool interior = (ti >= 20) && (ti + 51 <= 255) && (tj >= 20) && (tj + 51 <= 255);

    // ---- stage Y (clipped luminance, fp16) ----
    for (int idx = tid; idx < YD * YD; idx += NTHR) {
        int a = idx / YD, b = idx - a * YD;
        int g = (Ybi + a) * IMG + (Ybj + b);
        float r  = fminf(fmaxf(rgb[g], 0.f), 1.f);
        float gg = fminf(fmaxf(rgb[NPIX + g], 0.f), 1.f);
        float bb = fminf(fmaxf(rgb[2 * NPIX + g], 0.f), 1.f);
        Yreg[a][b] = (_Float16)(0.299f * r + 0.587f * gg + 0.114f * bb);
    }
    // ---- stage RGB1 taps at window-grid coords (UNclipped rgb; w-slot = 1) ----
    for (int idx = tid; idx < GR * GR; idx += NTHR) {
        int t = idx / GR, b = idx - t * GR;
        int g = refl(ti - 10 + t) * IMG + refl(tj - 10 + b);
        half4 c;
        c.x = (_Float16)rgb[g];
        c.y = (_Float16)rgb[NPIX + g];
        c.z = (_Float16)rgb[2 * NPIX + g];
        c.w = (_Float16)1.f;                   // weight accumulator partner
        *(half4*)&Creg4[t][b][0] = c;
    }
    // ---- col refl maps for all dv (edge tiles) ----
    if (!interior) {
        for (int idx = tid; idx < 21 * GR; idx += NTHR) {
            int d = idx / GR, c = idx - d * GR;
            cjTab[d][c] = (unsigned char)(refl(refl(tj - 10 + c) + (d - 10)) - Ybj);
        }
    }
    __syncthreads();   // staging complete — last barrier before epilogue

    const int lane = tid & 63;
    const int wv   = tid >> 6;               // wave id 0..7
    const bool hact = lane < GR;

    // ---- persistent y0 row (offset-invariant), 13 VGPRs ----
    half2_t y0h[26];
    if (hact) {
        if (interior) {
            const half2_t* q0 = (const half2_t*)&Yreg[lane + 10][10];
            #pragma unroll
            for (int i = 0; i < 26; ++i) y0h[i] = q0[i];
        } else {
            const _Float16* Y0row = &Yreg[refl(ti - 10 + lane) - Ybi][0];
            const unsigned char* cj0 = &cjTab[10][0];
            #pragma unroll
            for (int i = 0; i < 26; ++i) {
                half2_t v;
                v.x = Y0row[cj0[2 * i]];
                v.y = Y0row[cj0[2 * i + 1]];
                y0h[i] = v;
            }
        }
    }

    const float hv = fmaxf(hptr[0], 0.f);
    const float negI = -1.0f / (hv + 1e-8f);

    // v decomposition: lane -> (col pb, 16-row strip)
    const int pb  = lane & 31;
    const int s16 = (lane >> 5) << 4;        // 0 or 16

    half2_t accRG[16], accBW[16];            // packed fp16 accumulators (32 VGPRs)
    #pragma unroll
    for (int k = 0; k < 16; ++k) {
        accRG[k].x = (_Float16)0.f; accRG[k].y = (_Float16)0.f;
        accBW[k].x = (_Float16)0.f; accBW[k].y = (_Float16)0.f;
    }

    half2_t one; one.x = (_Float16)1.f; one.y = (_Float16)1.f;

    // ---- barrier-free offset loop: this wave owns offsets o = base + 64k ----
    for (int o = (int)blockIdx.y * 8 + wv; o < NOFF; o += 64) {
        const int oq = o / 21;
        const int du = oq - 10;
        const int dv = o - oq * 21 - 10;

        // ===== h-phase: lane = window row t, writes 32 col-sums to own strip =====
        if (hact) {
            const int t = lane;
            half2_t ff[26];
            if (interior) {
                if ((dv & 1) == 0) {
                    const half2_t* q1 = (const half2_t*)&Yreg[t + 10 + du][10 + dv];
                    #pragma unroll
                    for (int i = 0; i < 26; ++i) {
                        half2_t d2 = y0h[i] - q1[i];
                        ff[i] = d2 * d2;
                    }
                } else {
                    const half2_t* q1 = (const half2_t*)&Yreg[t + 10 + du][10 + dv - 1];
                    half2_t prev = q1[0];
                    #pragma unroll
                    for (int i = 0; i < 26; ++i) {
                        half2_t cur = q1[i + 1];
                        half2_t b; b.x = prev.y; b.y = cur.x;
                        half2_t d2 = y0h[i] - b;
                        ff[i] = d2 * d2;
                        prev = cur;
                    }
                }
            } else {
                const unsigned int* cw = (const unsigned int*)&cjTab[dv + 10][0];
                const _Float16* Y1row = &Yreg[refl(refl(ti - 10 + t) + du) - Ybi][0];
                #pragma unroll
                for (int i = 0; i < 26; ++i) {
                    unsigned int w0 = cw[i >> 1];
                    int sh = (i & 1) * 16;
                    _Float16 a0 = Y1row[(w0 >> sh) & 0xffu];
                    _Float16 a1 = Y1row[(w0 >> (sh + 8)) & 0xffu];
                    half2_t yv; yv.x = a0; yv.y = a1;
                    half2_t d2 = y0h[i] - yv;
                    ff[i] = d2 * d2;
                }
            }
            // two independent seeds: k=0 (f0..f20), k=16 (f16..f36)
            float s0f = 0.f, s1f = 0.f;
            #pragma unroll
            for (int i = 0; i < 10; ++i) s0f = FDOT2(ff[i], one, s0f);
            s0f += (float)ff[10].x;
            #pragma unroll
            for (int i = 8; i < 18; ++i) s1f = FDOT2(ff[i], one, s1f);
            s1f += (float)ff[18].x;
            _Float16 sA = (_Float16)s0f;
            _Float16 sB = (_Float16)s1f;
            hsT[wv][0][t]  = sA;
            hsT[wv][16][t] = sB;
            // two independent 15-step fp16 chains
            #pragma unroll
            for (int k = 1; k < 16; ++k) {
                {
                    int ja = 20 + k, jb = k - 1;
                    _Float16 fa = (ja & 1) ? ff[ja >> 1].y : ff[ja >> 1].x;
                    _Float16 fb = (jb & 1) ? ff[jb >> 1].y : ff[jb >> 1].x;
                    sA += (_Float16)(fa - fb);
                    hsT[wv][k][t] = sA;
                }
                {
                    int ja = 36 + k, jb = 15 + k;
                    _Float16 fa = (ja & 1) ? ff[ja >> 1].y : ff[ja >> 1].x;
                    _Float16 fb = (jb & 1) ? ff[jb >> 1].y : ff[jb >> 1].x;
                    sB += (_Float16)(fa - fb);
                    hsT[wv][16 + k][t] = sB;
                }
            }
        }

        // ===== v-phase: same wave, in-order DS -> no barrier needed =====
        {
            const half2_t* col2 = (const half2_t*)&hsT[wv][pb][s16];
            half2_t w2[18];                  // rows s16 .. s16+35
            #pragma unroll
            for (int i = 0; i < 18; ++i) w2[i] = col2[i];

            // two independent seeds: rows 0..20 and rows 8..28 (relative)
            float vs0 = 0.f, vs1 = 0.f;
            #pragma unroll
            for (int i = 0; i < 10; ++i) vs0 = FDOT2(w2[i], one, vs0);
            vs0 += (float)w2[10].x;
            #pragma unroll
            for (int i = 4; i < 14; ++i) vs1 = FDOT2(w2[i], one, vs1);
            vs1 += (float)w2[14].x;

            float vss[16];
            vss[0] = vs0;
            vss[8] = vs1;
            #pragma unroll
            for (int k = 0; k < 7; ++k) {
                {   // chain A: vss[1..7]
                    int ja = 21 + k, jb = k;
                    _Float16 fa = (ja & 1) ? w2[ja >> 1].y : w2[ja >> 1].x;
                    _Float16 fb = (jb & 1) ? w2[jb >> 1].y : w2[jb >> 1].x;
                    vss[k + 1] = vss[k] + (float)(_Float16)(fa - fb);
                }
                {   // chain B: vss[9..15]
                    int ja = 29 + k, jb = 8 + k;
                    _Float16 fa = (ja & 1) ? w2[ja >> 1].y : w2[ja >> 1].x;
                    _Float16 fb = (jb & 1) ? w2[jb >> 1].y : w2[jb >> 1].x;
                    vss[k + 9] = vss[k + 8] + (float)(_Float16)(fa - fb);
                }
            }

            const int cr = s16 + 10 + du;
            const int cc = pb + 10 + dv;
            #pragma unroll
            for (int k = 0; k < 16; ++k) {
                float dist = sqrtf(fmaxf(vss[k], 0.f));
                float w = __expf(dist * negI);
                _Float16 wh = (_Float16)w;
                half2_t w2v; w2v.x = wh; w2v.y = wh;
                const half2_t* cp = (const half2_t*)&Creg4[cr + k][cc][0];
                half2_t cRG = cp[0];         // (R, G)
                half2_t cBW = cp[1];         // (B, 1)
                accRG[k] = w2v * cRG + accRG[k];   // v_pk_fma_f16
                accBW[k] = w2v * cBW + accBW[k];
            }
        }
    }

    // ---- epilogue: merge 8 wave-streams via reused Creg LDS ----
    __syncthreads();                          // all taps consumed; Creg4 reusable
    float4* scratch = (float4*)&Creg4[0][0][0];   // 1024 x float4 = 16384 B
    #pragma unroll
    for (int w = 0; w < 8; ++w) {
        if (wv == w) {
            #pragma unroll
            for (int k = 0; k < 16; ++k) {
                int px = (s16 + k) * 32 + pb;
                float4 v = make_float4((float)accRG[k].x, (float)accRG[k].y,
                                       (float)accBW[k].x, (float)accBW[k].y);
                if (w == 0) scratch[px] = v;
                else {
                    float4 a = scratch[px];
                    scratch[px] = make_float4(a.x + v.x, a.y + v.y, a.z + v.z, a.w + v.w);
                }
            }
        }
        __syncthreads();
    }
    // ---- store: one float4 per pixel, coalesced ----
    for (int i = tid; i < TILE * TILE; i += NTHR) {
        float4 v = scratch[i];
        int gpix = (ti + (i >> 5)) * IMG + (tj + (i & 31));
        if (DIRECT) {
            partials[(size_t)blockIdx.y * NPIX + gpix] = v;
        } else {
            float* p = (float*)&partials[gpix];
            atomicAdd(p + 0, v.x);
            atomicAdd(p + 1, v.y);
            atomicAdd(p + 2, v.z);
            atomicAdd(p + 3, v.w);
        }
    }
}

template <int NGT>
__global__ __launch_bounds__(256)
void nlm_finalize(const float4* __restrict__ partials, float* __restrict__ out)
{
    int idx = blockIdx.x * blockDim.x + threadIdx.x;
    float r = 0.f, g = 0.f, b = 0.f, w = 0.f;
    #pragma unroll
    for (int gg = 0; gg < NGT; ++gg) {
        float4 p = partials[(size_t)gg * NPIX + idx];
        r += p.x; g += p.y; b += p.z; w += p.w;
    }
    float inv = 1.0f / w;   // sum(w) >= 1 (self offset contributes exp(0))
    out[idx]            = fminf(fmaxf(r * inv, 0.f), 1.f);
    out[NPIX + idx]     = fminf(fmaxf(g * inv, 0.f), 1.f);
    out[2 * NPIX + idx] = fminf(fmaxf(b * inv, 0.f), 1.f);
}

extern "C" void kernel_launch(void* const* d_in, const int* in_sizes, int n_in,
                              void* d_out, int out_size, void* d_ws, size_t ws_size,
                              hipStream_t stream) {
    (void)in_sizes; (void)n_in; (void)out_size;
    const float* rgb  = (const float*)d_in[0];
    const float* hptr = (const float*)d_in[1];
    float* out = (float*)d_out;
    float4* partials = (float4*)d_ws;

    const bool direct = ws_size >= (size_t)NGB * NPIX * sizeof(float4);  // 8.4 MB
    dim3 grid(64, NGB);   // 512 blocks = exactly 2 blocks/CU
    if (direct) {
        nlm_main<true><<<grid, NTHR, 0, stream>>>(rgb, hptr, partials);
        nlm_finalize<NGB><<<NPIX / 256, 256, 0, stream>>>(partials, out);
    } else {
        (void)hipMemsetAsync(partials, 0, (size_t)NPIX * sizeof(float4), stream);
        nlm_main<false><<<grid, NTHR, 0, stream>>>(rgb, hptr, partials);
        nlm_finalize<1><<<NPIX / 256, 256, 0, stream>>>(partials, out);
    }
}